// Round 1
// baseline (244.654 us; speedup 1.0000x reference)
//
#include <hip/hip_runtime.h>

typedef __bf16 bf16x8 __attribute__((ext_vector_type(8)));
typedef float f32x4 __attribute__((ext_vector_type(4)));
typedef unsigned short us8 __attribute__((ext_vector_type(8)));

__device__ __forceinline__ unsigned short f2bf(float f) {
  unsigned int u = __builtin_bit_cast(unsigned int, f);
  u += 0x7FFFu + ((u >> 16) & 1u);
  return (unsigned short)(u >> 16);
}

#define MFMA16(a, b, c) __builtin_amdgcn_mfma_f32_16x16x32_bf16(a, b, c, 0, 0, 0)

constexpr int Dm = 1024, Hh = 16, Ss = 2048, Bb = 2;

// ---------------- LayerNorm: fp32 [4096][1024] -> bf16 ----------------
__global__ __launch_bounds__(256) void ln_kernel(
    const float* __restrict__ x, const float* __restrict__ gamma,
    const float* __restrict__ beta, unsigned short* __restrict__ out) {
  const int row = blockIdx.x;
  const int t = threadIdx.x;
  const float4 v = reinterpret_cast<const float4*>(x + (size_t)row * Dm)[t];
  float s = v.x + v.y + v.z + v.w;
  float ss = v.x * v.x + v.y * v.y + v.z * v.z + v.w * v.w;
#pragma unroll
  for (int off = 1; off < 64; off <<= 1) {
    s += __shfl_xor(s, off);
    ss += __shfl_xor(ss, off);
  }
  __shared__ float sb[8];
  const int lane = t & 63, wid = t >> 6;
  if (lane == 0) { sb[wid] = s; sb[4 + wid] = ss; }
  __syncthreads();
  s = sb[0] + sb[1] + sb[2] + sb[3];
  ss = sb[4] + sb[5] + sb[6] + sb[7];
  const float mu = s * (1.0f / Dm);
  const float var = ss * (1.0f / Dm) - mu * mu;
  const float rs = rsqrtf(var + 1e-5f);
  const float4 g = reinterpret_cast<const float4*>(gamma)[t];
  const float4 bt = reinterpret_cast<const float4*>(beta)[t];
  ushort4 pack;
  pack.x = f2bf((v.x - mu) * rs * g.x + bt.x);
  pack.y = f2bf((v.y - mu) * rs * g.y + bt.y);
  pack.z = f2bf((v.z - mu) * rs * g.z + bt.z);
  pack.w = f2bf((v.w - mu) * rs * g.w + bt.w);
  reinterpret_cast<ushort4*>(out + (size_t)row * Dm)[t] = pack;
}

// ------------- transpose fp32 [K][N] -> bf16 [N][K] -------------
__global__ __launch_bounds__(256) void transpose_kernel(
    const float* __restrict__ in, unsigned short* __restrict__ out, int K, int N) {
  __shared__ float tile[32][33];
  const int tx = threadIdx.x & 31, ty = threadIdx.x >> 5;
  const int n0 = blockIdx.x * 32, k0 = blockIdx.y * 32;
#pragma unroll
  for (int i = 0; i < 4; i++)
    tile[ty + i * 8][tx] = in[(size_t)(k0 + ty + i * 8) * N + n0 + tx];
  __syncthreads();
#pragma unroll
  for (int i = 0; i < 4; i++)
    out[(size_t)(n0 + ty + i * 8) * K + k0 + tx] = f2bf(tile[tx][ty + i * 8]);
}

// ------------- GEMM: A [M][K] bf16, Bt [N][K] bf16 -------------
// EPI==0: C -> bf16 (with q-scale on n<1024).  EPI==1: C -> f32 + bias + resid.
template <int EPI>
__global__ __launch_bounds__(256) void gemm_kernel(
    const unsigned short* __restrict__ A, const unsigned short* __restrict__ Bt,
    int M, int N, int K, unsigned short* __restrict__ Cbf,
    float* __restrict__ Cf, const float* __restrict__ bias,
    const float* __restrict__ resid) {
  __shared__ unsigned short Al[128][72];
  __shared__ unsigned short Bl[128][72];
  const int tid = threadIdx.x;
  const int lane = tid & 63, wid = tid >> 6;
  const int l15 = lane & 15, lg = lane >> 4;
  const int wm = wid >> 1, wn = wid & 1;
  const int bm = blockIdx.y * 128, bn = blockIdx.x * 128;
  f32x4 acc[4][4] = {};
  for (int k0 = 0; k0 < K; k0 += 64) {
    __syncthreads();
#pragma unroll
    for (int i = 0; i < 4; i++) {
      const int chunk = tid + i * 256;
      const int row = chunk >> 3, c8 = (chunk & 7) * 8;
      *reinterpret_cast<int4*>(&Al[row][c8]) =
          *reinterpret_cast<const int4*>(&A[(size_t)(bm + row) * K + k0 + c8]);
      *reinterpret_cast<int4*>(&Bl[row][c8]) =
          *reinterpret_cast<const int4*>(&Bt[(size_t)(bn + row) * K + k0 + c8]);
    }
    __syncthreads();
#pragma unroll
    for (int kk = 0; kk < 2; kk++) {
      bf16x8 af[4], bfr[4];
#pragma unroll
      for (int mi = 0; mi < 4; mi++)
        af[mi] = *reinterpret_cast<const bf16x8*>(&Al[wm * 64 + mi * 16 + l15][kk * 32 + lg * 8]);
#pragma unroll
      for (int nj = 0; nj < 4; nj++)
        bfr[nj] = *reinterpret_cast<const bf16x8*>(&Bl[wn * 64 + nj * 16 + l15][kk * 32 + lg * 8]);
#pragma unroll
      for (int mi = 0; mi < 4; mi++)
#pragma unroll
        for (int nj = 0; nj < 4; nj++)
          acc[mi][nj] = MFMA16(af[mi], bfr[nj], acc[mi][nj]);
    }
  }
#pragma unroll
  for (int mi = 0; mi < 4; mi++)
#pragma unroll
    for (int nj = 0; nj < 4; nj++) {
      const int m = bm + wm * 64 + mi * 16 + lg * 4;
      const int n = bn + wn * 64 + nj * 16 + l15;
#pragma unroll
      for (int r = 0; r < 4; r++) {
        const float v = acc[mi][nj][r];
        if (EPI == 0) {
          const float sc = (n < 1024) ? 0.125f : 1.0f;
          Cbf[(size_t)(m + r) * N + n] = f2bf(v * sc);
        } else {
          const size_t idx = (size_t)(m + r) * N + n;
          Cf[idx] = v + bias[n] + resid[idx];
        }
      }
    }
}

// ------------- V transpose: qkv[.., 2048+h*64+hd] -> vt [bh][hd][s] -------------
__global__ __launch_bounds__(256) void vtrans_kernel(
    const unsigned short* __restrict__ qkv, unsigned short* __restrict__ vt) {
  const int tid = blockIdx.x * 256 + threadIdx.x;  // 32*64*128 = 262144
  const int sc = tid & 127;
  const int hd = (tid >> 7) & 63;
  const int bh = tid >> 13;
  const int b = bh >> 4, h = bh & 15;
  const unsigned short* src = qkv + (size_t)(b * Ss) * 3072 + 2048 + h * 64 + hd;
  us8 a, c;
#pragma unroll
  for (int j = 0; j < 8; j++) a[j] = src[(size_t)(sc * 16 + j) * 3072];
#pragma unroll
  for (int j = 0; j < 8; j++) c[j] = src[(size_t)(sc * 16 + 8 + j) * 3072];
  unsigned short* dst = vt + (size_t)bh * 64 * Ss + (size_t)hd * Ss + sc * 16;
  *reinterpret_cast<us8*>(dst) = a;
  *reinterpret_cast<us8*>(dst + 8) = c;
}

// ------------- flash attention -------------
// grid: 512 = (b*16+h)*16 + qtile. 4 waves x 32 q-rows. KV tile = 64.
__global__ __launch_bounds__(256) void attn_kernel(
    const unsigned short* __restrict__ qkv, const unsigned short* __restrict__ vt,
    unsigned short* __restrict__ dots) {
  __shared__ unsigned short Kl[64][72];
  __shared__ unsigned short Vl[64][72];
  __shared__ unsigned short Pl[4][32][72];
  const int tid = threadIdx.x, lane = tid & 63, wid = tid >> 6;
  const int l15 = lane & 15, lg = lane >> 4;
  const int bh = blockIdx.x >> 4, qt = blockIdx.x & 15;
  const int b = bh >> 4, h = bh & 15;
  const int q0 = qt * 128 + wid * 32;
  const unsigned short* qbase = qkv + (size_t)(b * Ss) * 3072 + h * 64;
  const unsigned short* kbase = qkv + (size_t)(b * Ss) * 3072 + 1024 + h * 64;
  const unsigned short* vbase = vt + (size_t)bh * 64 * Ss;

  bf16x8 qf[2][2];
#pragma unroll
  for (int mi = 0; mi < 2; mi++)
#pragma unroll
    for (int kk = 0; kk < 2; kk++)
      qf[mi][kk] = *reinterpret_cast<const bf16x8*>(
          &qbase[(size_t)(q0 + mi * 16 + l15) * 3072 + kk * 32 + lg * 8]);

  f32x4 acc_o[2][4] = {};
  float mrow[2][4], lrow[2][4];
#pragma unroll
  for (int mi = 0; mi < 2; mi++)
#pragma unroll
    for (int r = 0; r < 4; r++) { mrow[mi][r] = -1e30f; lrow[mi][r] = 0.f; }

  const int srow = tid >> 2, sc8 = (tid & 3) * 16;
  for (int t0 = 0; t0 < Ss; t0 += 64) {
    __syncthreads();
    *reinterpret_cast<int4*>(&Kl[srow][sc8]) =
        *reinterpret_cast<const int4*>(&kbase[(size_t)(t0 + srow) * 3072 + sc8]);
    *reinterpret_cast<int4*>(&Kl[srow][sc8 + 8]) =
        *reinterpret_cast<const int4*>(&kbase[(size_t)(t0 + srow) * 3072 + sc8 + 8]);
    *reinterpret_cast<int4*>(&Vl[srow][sc8]) =
        *reinterpret_cast<const int4*>(&vbase[(size_t)srow * Ss + t0 + sc8]);
    *reinterpret_cast<int4*>(&Vl[srow][sc8 + 8]) =
        *reinterpret_cast<const int4*>(&vbase[(size_t)srow * Ss + t0 + sc8 + 8]);
    __syncthreads();

    // S = Q K^T  (A=Q frags, B=K rows as [n][k])
    f32x4 accs[2][4] = {};
#pragma unroll
    for (int kk = 0; kk < 2; kk++) {
      bf16x8 bfr[4];
#pragma unroll
      for (int nj = 0; nj < 4; nj++)
        bfr[nj] = *reinterpret_cast<const bf16x8*>(&Kl[nj * 16 + l15][kk * 32 + lg * 8]);
#pragma unroll
      for (int mi = 0; mi < 2; mi++)
#pragma unroll
        for (int nj = 0; nj < 4; nj++)
          accs[mi][nj] = MFMA16(qf[mi][kk], bfr[nj], accs[mi][nj]);
    }

    // online softmax (row = mi*16 + 4*lg + r; 16-lane col-group reduce)
#pragma unroll
    for (int mi = 0; mi < 2; mi++)
#pragma unroll
      for (int r = 0; r < 4; r++) {
        float tm = accs[mi][0][r];
#pragma unroll
        for (int nj = 1; nj < 4; nj++) tm = fmaxf(tm, accs[mi][nj][r]);
#pragma unroll
        for (int off = 1; off < 16; off <<= 1) tm = fmaxf(tm, __shfl_xor(tm, off));
        const float mnew = fmaxf(mrow[mi][r], tm);
        const float corr = __expf(mrow[mi][r] - mnew);
        mrow[mi][r] = mnew;
        float ps = 0.f;
#pragma unroll
        for (int nj = 0; nj < 4; nj++) {
          const float p = __expf(accs[mi][nj][r] - mnew);
          accs[mi][nj][r] = p;
          ps += p;
        }
#pragma unroll
        for (int off = 1; off < 16; off <<= 1) ps += __shfl_xor(ps, off);
        lrow[mi][r] = lrow[mi][r] * corr + ps;
#pragma unroll
        for (int nj = 0; nj < 4; nj++) acc_o[mi][nj][r] *= corr;
      }

    // P (acc layout) -> per-wave LDS in [row][kv] layout
#pragma unroll
    for (int mi = 0; mi < 2; mi++)
#pragma unroll
      for (int nj = 0; nj < 4; nj++)
#pragma unroll
        for (int r = 0; r < 4; r++)
          Pl[wid][mi * 16 + lg * 4 + r][nj * 16 + l15] = f2bf(accs[mi][nj][r]);
    asm volatile("s_waitcnt lgkmcnt(0)" ::: "memory");

    // O += P V   (A=P from LDS, B=V^T [hd][kv])
#pragma unroll
    for (int kk2 = 0; kk2 < 2; kk2++) {
      bf16x8 pf[2], vf[4];
#pragma unroll
      for (int mi = 0; mi < 2; mi++)
        pf[mi] = *reinterpret_cast<const bf16x8*>(&Pl[wid][mi * 16 + l15][kk2 * 32 + lg * 8]);
#pragma unroll
      for (int nj = 0; nj < 4; nj++)
        vf[nj] = *reinterpret_cast<const bf16x8*>(&Vl[nj * 16 + l15][kk2 * 32 + lg * 8]);
#pragma unroll
      for (int mi = 0; mi < 2; mi++)
#pragma unroll
        for (int nj = 0; nj < 4; nj++)
          acc_o[mi][nj] = MFMA16(pf[mi], vf[nj], acc_o[mi][nj]);
    }
  }

#pragma unroll
  for (int mi = 0; mi < 2; mi++)
#pragma unroll
    for (int nj = 0; nj < 4; nj++)
#pragma unroll
      for (int r = 0; r < 4; r++) {
        const int q = q0 + mi * 16 + lg * 4 + r;
        const int hd = nj * 16 + l15;
        const float v = acc_o[mi][nj][r] / lrow[mi][r];
        dots[(size_t)(b * Ss + q) * Dm + h * 64 + hd] = f2bf(v);
      }
}

extern "C" void kernel_launch(void* const* d_in, const int* in_sizes, int n_in,
                              void* d_out, int out_size, void* d_ws, size_t ws_size,
                              hipStream_t stream) {
  const float* tokens = (const float*)d_in[0];
  const float* ln_g = (const float*)d_in[1];
  const float* ln_b = (const float*)d_in[2];
  const float* w_qkv = (const float*)d_in[3];
  const float* w_proj = (const float*)d_in[4];
  const float* b_proj = (const float*)d_in[5];
  float* out = (float*)d_out;

  char* ws = (char*)d_ws;
  unsigned short* x_bf = (unsigned short*)(ws);              // 8 MB (reused as dots)
  unsigned short* wqkvT = (unsigned short*)(ws + 8388608);   // 6 MB
  unsigned short* wprojT = (unsigned short*)(ws + 14680064); // 2 MB
  unsigned short* qkvraw = (unsigned short*)(ws + 16777216); // 24 MB
  unsigned short* vt = (unsigned short*)(ws + 41943040);     // 8 MB
  unsigned short* dots = x_bf;

  ln_kernel<<<4096, 256, 0, stream>>>(tokens, ln_g, ln_b, x_bf);
  transpose_kernel<<<dim3(3072 / 32, 1024 / 32), 256, 0, stream>>>(w_qkv, wqkvT, 1024, 3072);
  transpose_kernel<<<dim3(1024 / 32, 1024 / 32), 256, 0, stream>>>(w_proj, wprojT, 1024, 1024);
  gemm_kernel<0><<<dim3(3072 / 128, 4096 / 128), 256, 0, stream>>>(
      x_bf, wqkvT, 4096, 3072, 1024, qkvraw, nullptr, nullptr, nullptr);
  vtrans_kernel<<<1024, 256, 0, stream>>>(qkvraw, vt);
  attn_kernel<<<512, 256, 0, stream>>>(qkvraw, vt, dots);
  gemm_kernel<1><<<dim3(1024 / 128, 4096 / 128), 256, 0, stream>>>(
      dots, wprojT, 4096, 1024, 1024, nullptr, out, b_proj, tokens);
}

// Round 2
// 191.658 us; speedup vs baseline: 1.2765x; 1.2765x over previous
//
#include <hip/hip_runtime.h>

typedef __bf16 bf16x8 __attribute__((ext_vector_type(8)));
typedef __bf16 bf16x4 __attribute__((ext_vector_type(4)));
typedef float f32x4 __attribute__((ext_vector_type(4)));
typedef unsigned short us8 __attribute__((ext_vector_type(8)));

__device__ __forceinline__ unsigned short f2bf(float f) {
  unsigned int u = __builtin_bit_cast(unsigned int, f);
  u += 0x7FFFu + ((u >> 16) & 1u);
  return (unsigned short)(u >> 16);
}

__device__ __forceinline__ void load_lds16(const void* g, void* l) {
  __builtin_amdgcn_global_load_lds(
      (const __attribute__((address_space(1))) unsigned int*)g,
      (__attribute__((address_space(3))) unsigned int*)l, 16, 0, 0);
}

#define MFMA16(a, b, c) __builtin_amdgcn_mfma_f32_16x16x32_bf16(a, b, c, 0, 0, 0)

constexpr int Dm = 1024, Ss = 2048;

// ---------------- LayerNorm: fp32 [4096][1024] -> bf16 ----------------
__global__ __launch_bounds__(256) void ln_kernel(
    const float* __restrict__ x, const float* __restrict__ gamma,
    const float* __restrict__ beta, unsigned short* __restrict__ out) {
  const int row = blockIdx.x;
  const int t = threadIdx.x;
  const float4 v = reinterpret_cast<const float4*>(x + (size_t)row * Dm)[t];
  float s = v.x + v.y + v.z + v.w;
  float ss = v.x * v.x + v.y * v.y + v.z * v.z + v.w * v.w;
#pragma unroll
  for (int off = 1; off < 64; off <<= 1) {
    s += __shfl_xor(s, off);
    ss += __shfl_xor(ss, off);
  }
  __shared__ float sb[8];
  const int lane = t & 63, wid = t >> 6;
  if (lane == 0) { sb[wid] = s; sb[4 + wid] = ss; }
  __syncthreads();
  s = sb[0] + sb[1] + sb[2] + sb[3];
  ss = sb[4] + sb[5] + sb[6] + sb[7];
  const float mu = s * (1.0f / Dm);
  const float var = ss * (1.0f / Dm) - mu * mu;
  const float rs = rsqrtf(var + 1e-5f);
  const float4 g = reinterpret_cast<const float4*>(gamma)[t];
  const float4 bt = reinterpret_cast<const float4*>(beta)[t];
  ushort4 pack;
  pack.x = f2bf((v.x - mu) * rs * g.x + bt.x);
  pack.y = f2bf((v.y - mu) * rs * g.y + bt.y);
  pack.z = f2bf((v.z - mu) * rs * g.z + bt.z);
  pack.w = f2bf((v.w - mu) * rs * g.w + bt.w);
  reinterpret_cast<ushort4*>(out + (size_t)row * Dm)[t] = pack;
}

// ------------- transpose fp32 [K][N] -> bf16 [N][K] -------------
__global__ __launch_bounds__(256) void transpose_kernel(
    const float* __restrict__ in, unsigned short* __restrict__ out, int K, int N) {
  __shared__ float tile[32][33];
  const int tx = threadIdx.x & 31, ty = threadIdx.x >> 5;
  const int n0 = blockIdx.x * 32, k0 = blockIdx.y * 32;
#pragma unroll
  for (int i = 0; i < 4; i++)
    tile[ty + i * 8][tx] = in[(size_t)(k0 + ty + i * 8) * N + n0 + tx];
  __syncthreads();
#pragma unroll
  for (int i = 0; i < 4; i++)
    out[(size_t)(n0 + ty + i * 8) * K + k0 + tx] = f2bf(tile[tx][ty + i * 8]);
}

// ------------- GEMM: A [M][K] bf16, Bt [N][K] bf16 -------------
// EPI==0: C -> bf16 (Q cols scaled by 0.125*log2(e)).  EPI==1: C -> f32 + bias + resid.
template <int EPI>
__global__ __launch_bounds__(256) void gemm_kernel(
    const unsigned short* __restrict__ A, const unsigned short* __restrict__ Bt,
    int M, int N, int K, unsigned short* __restrict__ Cbf,
    float* __restrict__ Cf, const float* __restrict__ bias,
    const float* __restrict__ resid) {
  __shared__ unsigned short Al[128][72];
  __shared__ unsigned short Bl[128][72];
  const int tid = threadIdx.x;
  const int lane = tid & 63, wid = tid >> 6;
  const int l15 = lane & 15, lg = lane >> 4;
  const int wm = wid >> 1, wn = wid & 1;
  const int bm = blockIdx.y * 128, bn = blockIdx.x * 128;
  f32x4 acc[4][4] = {};
  for (int k0 = 0; k0 < K; k0 += 64) {
    __syncthreads();
#pragma unroll
    for (int i = 0; i < 4; i++) {
      const int chunk = tid + i * 256;
      const int row = chunk >> 3, c8 = (chunk & 7) * 8;
      *reinterpret_cast<int4*>(&Al[row][c8]) =
          *reinterpret_cast<const int4*>(&A[(size_t)(bm + row) * K + k0 + c8]);
      *reinterpret_cast<int4*>(&Bl[row][c8]) =
          *reinterpret_cast<const int4*>(&Bt[(size_t)(bn + row) * K + k0 + c8]);
    }
    __syncthreads();
#pragma unroll
    for (int kk = 0; kk < 2; kk++) {
      bf16x8 af[4], bfr[4];
#pragma unroll
      for (int mi = 0; mi < 4; mi++)
        af[mi] = *reinterpret_cast<const bf16x8*>(&Al[wm * 64 + mi * 16 + l15][kk * 32 + lg * 8]);
#pragma unroll
      for (int nj = 0; nj < 4; nj++)
        bfr[nj] = *reinterpret_cast<const bf16x8*>(&Bl[wn * 64 + nj * 16 + l15][kk * 32 + lg * 8]);
#pragma unroll
      for (int mi = 0; mi < 4; mi++)
#pragma unroll
        for (int nj = 0; nj < 4; nj++)
          acc[mi][nj] = MFMA16(af[mi], bfr[nj], acc[mi][nj]);
    }
  }
#pragma unroll
  for (int mi = 0; mi < 4; mi++)
#pragma unroll
    for (int nj = 0; nj < 4; nj++) {
      const int m = bm + wm * 64 + mi * 16 + lg * 4;
      const int n = bn + wn * 64 + nj * 16 + l15;
#pragma unroll
      for (int r = 0; r < 4; r++) {
        const float v = acc[mi][nj][r];
        if (EPI == 0) {
          // fold attention scale 0.125 and log2(e) (softmax done in base-2) into Q
          const float sc = (n < 1024) ? 0.180336880f : 1.0f;
          Cbf[(size_t)(m + r) * N + n] = f2bf(v * sc);
        } else {
          const size_t idx = (size_t)(m + r) * N + n;
          Cf[idx] = v + bias[n] + resid[idx];
        }
      }
    }
}

// ------------- V transpose: qkv[.., 2048+h*64+hd] -> vt [bh][hd][s] -------------
__global__ __launch_bounds__(256) void vtrans_kernel(
    const unsigned short* __restrict__ qkv, unsigned short* __restrict__ vt) {
  const int tid = blockIdx.x * 256 + threadIdx.x;  // 262144
  const int sc = tid & 127;
  const int hd = (tid >> 7) & 63;
  const int bh = tid >> 13;
  const int b = bh >> 4, h = bh & 15;
  const unsigned short* src = qkv + (size_t)(b * Ss) * 3072 + 2048 + h * 64 + hd;
  us8 a, c;
#pragma unroll
  for (int j = 0; j < 8; j++) a[j] = src[(size_t)(sc * 16 + j) * 3072];
#pragma unroll
  for (int j = 0; j < 8; j++) c[j] = src[(size_t)(sc * 16 + 8 + j) * 3072];
  unsigned short* dst = vt + (size_t)bh * 64 * Ss + (size_t)hd * Ss + sc * 16;
  *reinterpret_cast<us8*>(dst) = a;
  *reinterpret_cast<us8*>(dst + 8) = c;
}

// ------------- flash attention (swapped-QK, dbuf global_load_lds staging) -------------
// grid 512: XCD-chunked remap -> (bh, qt). 4 waves x 32 q-rows, KVBLK=64.
__global__ __launch_bounds__(256) void attn_kernel(
    const unsigned short* __restrict__ qkv, const unsigned short* __restrict__ vt,
    unsigned short* __restrict__ dots) {
  __shared__ unsigned short Kb[2][64 * 64];  // swizzled content, linear [64][64]
  __shared__ unsigned short Vb[2][64 * 64];
  __shared__ unsigned short Pl[4][32][72];
  const int tid = threadIdx.x, lane = tid & 63, wid = tid >> 6;
  const int l15 = lane & 15, lg = lane >> 4;
  // XCD swizzle: 512 blocks, 8 XCDs, 64 contiguous logical blocks per XCD
  const int lb = (blockIdx.x & 7) * 64 + (blockIdx.x >> 3);
  const int bh = lb >> 4, qt = lb & 15;
  const int b = bh >> 4, h = bh & 15;
  const int q0 = qt * 128 + wid * 32;
  const unsigned short* qbase = qkv + (size_t)(b * Ss) * 3072 + h * 64;
  const char* kbase = (const char*)(qkv + (size_t)(b * Ss) * 3072 + 1024 + h * 64);
  const char* vbase = (const char*)(vt + (size_t)bh * 64 * Ss);

  // Q fragments in registers (B-operand layout: row=q, k=d)
  bf16x8 qf[2][2];
#pragma unroll
  for (int qj = 0; qj < 2; qj++)
#pragma unroll
    for (int kk = 0; kk < 2; kk++)
      qf[qj][kk] = *reinterpret_cast<const bf16x8*>(
          &qbase[(size_t)(q0 + qj * 16 + l15) * 3072 + kk * 32 + lg * 8]);

  f32x4 acc_o[2][4] = {};
  float mq[2] = {-3.0e38f, -3.0e38f}, lq[2] = {0.f, 0.f};

  // staging geometry: per wave 16 rows of K and V per tile, 2 load_lds each
  const int srow = (lane >> 3) & 7;        // row within 8-row chunk
  const int scb = (lane & 7) * 16;         // byte col within 128B row
  const int swz = scb ^ (srow << 4);       // inverse-swizzled source col

#define STAGE(bufi, t0v)                                                          \
  {                                                                               \
    _Pragma("unroll") for (int c = 0; c < 2; c++) {                               \
      const int kr = wid * 16 + c * 8 + srow;                                     \
      load_lds16(kbase + (size_t)((t0v) + kr) * 6144 + swz,                       \
                 (char*)&Kb[bufi][0] + wid * 2048 + c * 1024);                    \
      load_lds16(vbase + (size_t)kr * 4096 + (t0v) * 2 + swz,                     \
                 (char*)&Vb[bufi][0] + wid * 2048 + c * 1024);                    \
    }                                                                             \
  }

  STAGE(0, 0);
  __syncthreads();

  for (int it = 0; it < 32; it++) {
    const int cur = it & 1;
    if (it + 1 < 32) STAGE(cur ^ 1, (it + 1) * 64);

    const char* kcur = (const char*)&Kb[cur][0];
    const char* vcur = (const char*)&Vb[cur][0];

    // S^T = K Q^T : A=K rows (kv), B=Q rows (q). lane: col q=l15, rows kv=lg*4+r
    f32x4 accs[4][2] = {};
#pragma unroll
    for (int kk = 0; kk < 2; kk++) {
      bf16x8 kf[4];
#pragma unroll
      for (int kvi = 0; kvi < 4; kvi++) {
        const int rk = kvi * 16 + l15;
        kf[kvi] = *(const bf16x8*)(kcur + rk * 128 +
                                   ((kk * 64 + lg * 16) ^ ((l15 & 7) << 4)));
      }
#pragma unroll
      for (int kvi = 0; kvi < 4; kvi++)
#pragma unroll
        for (int qj = 0; qj < 2; qj++)
          accs[kvi][qj] = MFMA16(kf[kvi], qf[qj][kk], accs[kvi][qj]);
    }

    // in-lane online softmax (base-2; scale folded into Q)
    float corrv[2];
#pragma unroll
    for (int qj = 0; qj < 2; qj++) {
      float tm = -3.0e38f;
#pragma unroll
      for (int kvi = 0; kvi < 4; kvi++)
#pragma unroll
        for (int r = 0; r < 4; r++) tm = fmaxf(tm, accs[kvi][qj][r]);
      tm = fmaxf(tm, __shfl_xor(tm, 16));
      tm = fmaxf(tm, __shfl_xor(tm, 32));
      const float mnew = fmaxf(mq[qj], tm);
      corrv[qj] = exp2f(mq[qj] - mnew);
      mq[qj] = mnew;
      float ps = 0.f;
#pragma unroll
      for (int kvi = 0; kvi < 4; kvi++) {
        bf16x4 pk;
#pragma unroll
        for (int r = 0; r < 4; r++) {
          const float p = exp2f(accs[kvi][qj][r] - mnew);
          ps += p;
          pk[r] = (__bf16)p;
        }
        *(bf16x4*)&Pl[wid][qj * 16 + l15][kvi * 16 + lg * 4] = pk;
      }
      ps += __shfl_xor(ps, 16);
      ps += __shfl_xor(ps, 32);
      lq[qj] = lq[qj] * corrv[qj] + ps;
    }

    // rescale O (redistribute corr from q=l15 layout to q=lg*4+r layout)
#pragma unroll
    for (int mi = 0; mi < 2; mi++)
#pragma unroll
      for (int r = 0; r < 4; r++) {
        const float c = __shfl(corrv[mi], lg * 4 + r, 16);
#pragma unroll
        for (int nj = 0; nj < 4; nj++) acc_o[mi][nj][r] *= c;
      }

    asm volatile("s_waitcnt lgkmcnt(0)" ::: "memory");

    // O += P V  (A=P rows q, B=V^T rows hd)
#pragma unroll
    for (int kk2 = 0; kk2 < 2; kk2++) {
      bf16x8 pf[2], vf[4];
#pragma unroll
      for (int mi = 0; mi < 2; mi++)
        pf[mi] = *(const bf16x8*)((const char*)&Pl[wid][mi * 16 + l15][0] +
                                  kk2 * 64 + lg * 16);
#pragma unroll
      for (int nj = 0; nj < 4; nj++) {
        const int rv = nj * 16 + l15;
        vf[nj] = *(const bf16x8*)(vcur + rv * 128 +
                                  ((kk2 * 64 + lg * 16) ^ ((l15 & 7) << 4)));
      }
#pragma unroll
      for (int mi = 0; mi < 2; mi++)
#pragma unroll
        for (int nj = 0; nj < 4; nj++)
          acc_o[mi][nj] = MFMA16(pf[mi], vf[nj], acc_o[mi][nj]);
    }

    __syncthreads();
  }

#pragma unroll
  for (int mi = 0; mi < 2; mi++) {
    const float rl = 1.0f / lq[mi];
#pragma unroll
    for (int r = 0; r < 4; r++) {
      const float rn = __shfl(rl, lg * 4 + r, 16);
      const int q = q0 + mi * 16 + lg * 4 + r;
#pragma unroll
      for (int nj = 0; nj < 4; nj++)
        dots[(size_t)(b * Ss + q) * Dm + h * 64 + nj * 16 + l15] =
            f2bf(acc_o[mi][nj][r] * rn);
    }
  }
}

extern "C" void kernel_launch(void* const* d_in, const int* in_sizes, int n_in,
                              void* d_out, int out_size, void* d_ws, size_t ws_size,
                              hipStream_t stream) {
  const float* tokens = (const float*)d_in[0];
  const float* ln_g = (const float*)d_in[1];
  const float* ln_b = (const float*)d_in[2];
  const float* w_qkv = (const float*)d_in[3];
  const float* w_proj = (const float*)d_in[4];
  const float* b_proj = (const float*)d_in[5];
  float* out = (float*)d_out;

  char* ws = (char*)d_ws;
  unsigned short* x_bf = (unsigned short*)(ws);              // 8 MB (reused as dots)
  unsigned short* wqkvT = (unsigned short*)(ws + 8388608);   // 6 MB
  unsigned short* wprojT = (unsigned short*)(ws + 14680064); // 2 MB
  unsigned short* qkvraw = (unsigned short*)(ws + 16777216); // 24 MB
  unsigned short* vt = (unsigned short*)(ws + 41943040);     // 8 MB
  unsigned short* dots = x_bf;

  ln_kernel<<<4096, 256, 0, stream>>>(tokens, ln_g, ln_b, x_bf);
  transpose_kernel<<<dim3(3072 / 32, 1024 / 32), 256, 0, stream>>>(w_qkv, wqkvT, 1024, 3072);
  transpose_kernel<<<dim3(1024 / 32, 1024 / 32), 256, 0, stream>>>(w_proj, wprojT, 1024, 1024);
  gemm_kernel<0><<<dim3(3072 / 128, 4096 / 128), 256, 0, stream>>>(
      x_bf, wqkvT, 4096, 3072, 1024, qkvraw, nullptr, nullptr, nullptr);
  vtrans_kernel<<<1024, 256, 0, stream>>>(qkvraw, vt);
  attn_kernel<<<512, 256, 0, stream>>>(qkvraw, vt, dots);
  gemm_kernel<1><<<dim3(1024 / 128, 4096 / 128), 256, 0, stream>>>(
      dots, wprojT, 4096, 1024, 1024, nullptr, out, b_proj, tokens);
}

// Round 3
// 158.533 us; speedup vs baseline: 1.5432x; 1.2089x over previous
//
#include <hip/hip_runtime.h>

typedef __bf16 bf16x8 __attribute__((ext_vector_type(8)));
typedef __bf16 bf16x4 __attribute__((ext_vector_type(4)));
typedef float f32x4 __attribute__((ext_vector_type(4)));
typedef unsigned short us8 __attribute__((ext_vector_type(8)));

__device__ __forceinline__ unsigned short f2bf(float f) {
  unsigned int u = __builtin_bit_cast(unsigned int, f);
  u += 0x7FFFu + ((u >> 16) & 1u);
  return (unsigned short)(u >> 16);
}

__device__ __forceinline__ void load_lds16(const void* g, void* l) {
  __builtin_amdgcn_global_load_lds(
      (const __attribute__((address_space(1))) unsigned int*)g,
      (__attribute__((address_space(3))) unsigned int*)l, 16, 0, 0);
}

#define MFMA16(a, b, c) __builtin_amdgcn_mfma_f32_16x16x32_bf16(a, b, c, 0, 0, 0)

constexpr int Dm = 1024, Ss = 2048;

// ---------------- LayerNorm: fp32 [4096][1024] -> bf16 ----------------
__global__ __launch_bounds__(256) void ln_kernel(
    const float* __restrict__ x, const float* __restrict__ gamma,
    const float* __restrict__ beta, unsigned short* __restrict__ out) {
  const int row = blockIdx.x;
  const int t = threadIdx.x;
  const float4 v = reinterpret_cast<const float4*>(x + (size_t)row * Dm)[t];
  float s = v.x + v.y + v.z + v.w;
  float ss = v.x * v.x + v.y * v.y + v.z * v.z + v.w * v.w;
#pragma unroll
  for (int off = 1; off < 64; off <<= 1) {
    s += __shfl_xor(s, off);
    ss += __shfl_xor(ss, off);
  }
  __shared__ float sb[8];
  const int lane = t & 63, wid = t >> 6;
  if (lane == 0) { sb[wid] = s; sb[4 + wid] = ss; }
  __syncthreads();
  s = sb[0] + sb[1] + sb[2] + sb[3];
  ss = sb[4] + sb[5] + sb[6] + sb[7];
  const float mu = s * (1.0f / Dm);
  const float var = ss * (1.0f / Dm) - mu * mu;
  const float rs = rsqrtf(var + 1e-5f);
  const float4 g = reinterpret_cast<const float4*>(gamma)[t];
  const float4 bt = reinterpret_cast<const float4*>(beta)[t];
  ushort4 pack;
  pack.x = f2bf((v.x - mu) * rs * g.x + bt.x);
  pack.y = f2bf((v.y - mu) * rs * g.y + bt.y);
  pack.z = f2bf((v.z - mu) * rs * g.z + bt.z);
  pack.w = f2bf((v.w - mu) * rs * g.w + bt.w);
  reinterpret_cast<ushort4*>(out + (size_t)row * Dm)[t] = pack;
}

// ------------- transpose fp32 [K][N] -> bf16 [N][K] -------------
__global__ __launch_bounds__(256) void transpose_kernel(
    const float* __restrict__ in, unsigned short* __restrict__ out, int K, int N) {
  __shared__ float tile[32][33];
  const int tx = threadIdx.x & 31, ty = threadIdx.x >> 5;
  const int n0 = blockIdx.x * 32, k0 = blockIdx.y * 32;
#pragma unroll
  for (int i = 0; i < 4; i++)
    tile[ty + i * 8][tx] = in[(size_t)(k0 + ty + i * 8) * N + n0 + tx];
  __syncthreads();
#pragma unroll
  for (int i = 0; i < 4; i++)
    out[(size_t)(n0 + ty + i * 8) * K + k0 + tx] = f2bf(tile[tx][ty + i * 8]);
}

// ------------- GEMM (m97 structure): A [M][K] bf16, Bt [N][K] bf16 -------------
// global_load_lds staging, XOR-swizzled LDS, XCD-chunked 1-D grid.
// EPI==0: C -> bf16 (Q cols scaled).  EPI==1: C -> f32 + bias + resid.
template <int EPI>
__global__ __launch_bounds__(256) void gemm_kernel(
    const unsigned short* __restrict__ A, const unsigned short* __restrict__ Bt,
    int N, int K, int nbx, unsigned short* __restrict__ Cbf,
    float* __restrict__ Cf, const float* __restrict__ bias,
    const float* __restrict__ resid) {
  __shared__ unsigned short Al[128 * 64];
  __shared__ unsigned short Bl[128 * 64];
  const int tid = threadIdx.x;
  const int lane = tid & 63, wid = tid >> 6;
  const int l15 = lane & 15, lg = lane >> 4;
  const int wm = wid >> 1, wn = wid & 1;
  // XCD-chunked swizzle (grid % 8 == 0 for both launches)
  const int cpx = gridDim.x >> 3;
  const int lb = (blockIdx.x & 7) * cpx + (blockIdx.x >> 3);
  const int bx = lb % nbx, by = lb / nbx;
  const int bm = by * 128, bn = bx * 128;
  const int r8 = lane >> 3;
  const int swz = ((lane & 7) * 16) ^ (r8 << 4);  // inverse-swizzled source byte col
  const char* Ab = (const char*)A;
  const char* Bb = (const char*)Bt;
  f32x4 acc[4][4] = {};
  for (int k0 = 0; k0 < K; k0 += 64) {
    __syncthreads();
#pragma unroll
    for (int p = 0; p < 4; p++) {
      const int row = p * 32 + wid * 8 + r8;
      load_lds16(Ab + ((size_t)(bm + row) * K + k0) * 2 + swz,
                 (char*)Al + p * 4096 + wid * 1024);
      load_lds16(Bb + ((size_t)(bn + row) * K + k0) * 2 + swz,
                 (char*)Bl + p * 4096 + wid * 1024);
    }
    __syncthreads();
#pragma unroll
    for (int kk = 0; kk < 2; kk++) {
      bf16x8 af[4], bfr[4];
#pragma unroll
      for (int mi = 0; mi < 4; mi++) {
        const int row = wm * 64 + mi * 16 + l15;
        af[mi] = *(const bf16x8*)((const char*)Al + row * 128 +
                                  ((kk * 64 + lg * 16) ^ ((row & 7) << 4)));
      }
#pragma unroll
      for (int nj = 0; nj < 4; nj++) {
        const int row = wn * 64 + nj * 16 + l15;
        bfr[nj] = *(const bf16x8*)((const char*)Bl + row * 128 +
                                   ((kk * 64 + lg * 16) ^ ((row & 7) << 4)));
      }
#pragma unroll
      for (int mi = 0; mi < 4; mi++)
#pragma unroll
        for (int nj = 0; nj < 4; nj++)
          acc[mi][nj] = MFMA16(af[mi], bfr[nj], acc[mi][nj]);
    }
  }
#pragma unroll
  for (int mi = 0; mi < 4; mi++)
#pragma unroll
    for (int nj = 0; nj < 4; nj++) {
      const int m = bm + wm * 64 + mi * 16 + lg * 4;
      const int n = bn + wn * 64 + nj * 16 + l15;
#pragma unroll
      for (int r = 0; r < 4; r++) {
        const float v = acc[mi][nj][r];
        if (EPI == 0) {
          // fold attention scale 0.125 and log2(e) (base-2 softmax) into Q
          const float sc = (n < 1024) ? 0.180336880f : 1.0f;
          Cbf[(size_t)(m + r) * N + n] = f2bf(v * sc);
        } else {
          const size_t idx = (size_t)(m + r) * N + n;
          Cf[idx] = v + bias[n] + resid[idx];
        }
      }
    }
}

// ------------- V transpose (LDS-tiled): qkv V-block -> vt [bh][hd][s] -------------
__global__ __launch_bounds__(256) void vtrans_kernel(
    const unsigned short* __restrict__ qkv, unsigned short* __restrict__ vt) {
  __shared__ unsigned short tile[64][72];
  const int bh = blockIdx.x >> 5, st = blockIdx.x & 31;
  const int b = bh >> 4, h = bh & 15;
  const int s0 = st * 64;
  const int tid = threadIdx.x;
  const unsigned short* src = qkv + (size_t)(b * Ss) * 3072 + 2048 + h * 64;
#pragma unroll
  for (int p = 0; p < 2; p++) {
    const int ch = p * 256 + tid;
    const int r = ch >> 3, c8 = (ch & 7) * 8;
    *(us8*)&tile[r][c8] = *(const us8*)&src[(size_t)(s0 + r) * 3072 + c8];
  }
  __syncthreads();
#pragma unroll
  for (int p = 0; p < 2; p++) {
    const int ch = p * 256 + tid;
    const int hd = ch >> 3, s8 = (ch & 7) * 8;
    us8 v;
#pragma unroll
    for (int j = 0; j < 8; j++) v[j] = tile[s8 + j][hd];
    *(us8*)(vt + (size_t)bh * 64 * Ss + (size_t)hd * Ss + s0 + s8) = v;
  }
}

// ------------- flash attention: swapped-QK, counted-vmcnt dbuf, defer-max -------------
__global__ __launch_bounds__(256) void attn_kernel(
    const unsigned short* __restrict__ qkv, const unsigned short* __restrict__ vt,
    unsigned short* __restrict__ dots) {
  __shared__ unsigned short Kb[2][64 * 64];  // swizzled content, linear layout
  __shared__ unsigned short Vb[2][64 * 64];
  __shared__ unsigned short Pl[4][32][72];
  const int tid = threadIdx.x, lane = tid & 63, wid = tid >> 6;
  const int l15 = lane & 15, lg = lane >> 4;
  const int lb = (blockIdx.x & 7) * 64 + (blockIdx.x >> 3);
  const int bh = lb >> 4, qt = lb & 15;
  const int b = bh >> 4, h = bh & 15;
  const int q0 = qt * 128 + wid * 32;
  const unsigned short* qbase = qkv + (size_t)(b * Ss) * 3072 + h * 64;
  const char* kbase = (const char*)(qkv + (size_t)(b * Ss) * 3072 + 1024 + h * 64);
  const char* vbase = (const char*)(vt + (size_t)bh * 64 * Ss);

  bf16x8 qf[2][2];
#pragma unroll
  for (int qj = 0; qj < 2; qj++)
#pragma unroll
    for (int kk = 0; kk < 2; kk++)
      qf[qj][kk] = *reinterpret_cast<const bf16x8*>(
          &qbase[(size_t)(q0 + qj * 16 + l15) * 3072 + kk * 32 + lg * 8]);

  f32x4 acc_o[2][4] = {};
  float mq[2] = {-3.0e38f, -3.0e38f}, lq[2] = {0.f, 0.f};

  const int srow = (lane >> 3) & 7;
  const int scb = (lane & 7) * 16;
  const int swz = scb ^ (srow << 4);

// issue K pair first, then V pair (vmcnt(2) waits K only)
#define STAGE(bufi, t0v)                                                          \
  {                                                                               \
    _Pragma("unroll") for (int c = 0; c < 2; c++) {                               \
      const int kr = wid * 16 + c * 8 + srow;                                     \
      load_lds16(kbase + (size_t)((t0v) + kr) * 6144 + swz,                       \
                 (char*)&Kb[bufi][0] + wid * 2048 + c * 1024);                    \
    }                                                                             \
    _Pragma("unroll") for (int c = 0; c < 2; c++) {                               \
      const int kr = wid * 16 + c * 8 + srow;                                     \
      load_lds16(vbase + (size_t)kr * 4096 + (t0v) * 2 + swz,                     \
                 (char*)&Vb[bufi][0] + wid * 2048 + c * 1024);                    \
    }                                                                             \
  }

  STAGE(0, 0);

  for (int it = 0; it < 32; it++) {
    const int cur = it & 1;
    // K(cur) ready across all waves; V may still be in flight
    asm volatile("s_waitcnt vmcnt(2)\ns_barrier" ::: "memory");

    const char* kcur = (const char*)&Kb[cur][0];
    const char* vcur = (const char*)&Vb[cur][0];

    // S^T = K Q^T : lane holds q-col = l15, kv rows = lg*4+r (+16*kvi)
    f32x4 accs[4][2] = {};
#pragma unroll
    for (int kk = 0; kk < 2; kk++) {
      bf16x8 kf[4];
#pragma unroll
      for (int kvi = 0; kvi < 4; kvi++) {
        const int rk = kvi * 16 + l15;
        kf[kvi] = *(const bf16x8*)(kcur + rk * 128 +
                                   ((kk * 64 + lg * 16) ^ ((l15 & 7) << 4)));
      }
#pragma unroll
      for (int kvi = 0; kvi < 4; kvi++)
#pragma unroll
        for (int qj = 0; qj < 2; qj++)
          accs[kvi][qj] = MFMA16(kf[kvi], qf[qj][kk], accs[kvi][qj]);
    }

    // tile max per q (in-lane 16 + cross-group shfl)
    float tm[2];
#pragma unroll
    for (int qj = 0; qj < 2; qj++) {
      float a = fmaxf(fmaxf(accs[0][qj][0], accs[0][qj][1]),
                      fmaxf(accs[0][qj][2], accs[0][qj][3]));
      float c = fmaxf(fmaxf(accs[1][qj][0], accs[1][qj][1]),
                      fmaxf(accs[1][qj][2], accs[1][qj][3]));
      float d = fmaxf(fmaxf(accs[2][qj][0], accs[2][qj][1]),
                      fmaxf(accs[2][qj][2], accs[2][qj][3]));
      float e = fmaxf(fmaxf(accs[3][qj][0], accs[3][qj][1]),
                      fmaxf(accs[3][qj][2], accs[3][qj][3]));
      float t = fmaxf(fmaxf(a, c), fmaxf(d, e));
      t = fmaxf(t, __shfl_xor(t, 16));
      t = fmaxf(t, __shfl_xor(t, 32));
      tm[qj] = t;
    }

    // defer-max: only rescale when max grew by > 8 (base-2 units)
    if (!__all((tm[0] <= mq[0] + 8.f) && (tm[1] <= mq[1] + 8.f))) {
      float corrv[2];
#pragma unroll
      for (int qj = 0; qj < 2; qj++) {
        const float mnew = fmaxf(mq[qj], tm[qj]);
        corrv[qj] = exp2f(mq[qj] - mnew);
        mq[qj] = mnew;
        lq[qj] *= corrv[qj];
      }
#pragma unroll
      for (int mi = 0; mi < 2; mi++)
#pragma unroll
        for (int r = 0; r < 4; r++) {
          const float c = __shfl(corrv[mi], lg * 4 + r, 16);
#pragma unroll
          for (int nj = 0; nj < 4; nj++) acc_o[mi][nj][r] *= c;
        }
    }

    // P = exp2(S - m), write to per-wave LDS, accumulate row-sum
#pragma unroll
    for (int qj = 0; qj < 2; qj++) {
      float ps = 0.f;
#pragma unroll
      for (int kvi = 0; kvi < 4; kvi++) {
        bf16x4 pk;
#pragma unroll
        for (int r = 0; r < 4; r++) {
          const float p = exp2f(accs[kvi][qj][r] - mq[qj]);
          ps += p;
          pk[r] = (__bf16)p;
        }
        *(bf16x4*)&Pl[wid][qj * 16 + l15][kvi * 16 + lg * 4] = pk;
      }
      ps += __shfl_xor(ps, 16);
      ps += __shfl_xor(ps, 32);
      lq[qj] += ps;
    }

    // V(cur) ready across all waves; P writes drained by lgkmcnt(0)
    asm volatile("s_waitcnt vmcnt(0) lgkmcnt(0)\ns_barrier" ::: "memory");

    // O += P V
#pragma unroll
    for (int kk2 = 0; kk2 < 2; kk2++) {
      bf16x8 pf[2], vf[4];
#pragma unroll
      for (int mi = 0; mi < 2; mi++)
        pf[mi] = *(const bf16x8*)((const char*)&Pl[wid][mi * 16 + l15][0] +
                                  kk2 * 64 + lg * 16);
#pragma unroll
      for (int nj = 0; nj < 4; nj++) {
        const int rv = nj * 16 + l15;
        vf[nj] = *(const bf16x8*)(vcur + rv * 128 +
                                  ((kk2 * 64 + lg * 16) ^ ((l15 & 7) << 4)));
      }
#pragma unroll
      for (int mi = 0; mi < 2; mi++)
#pragma unroll
        for (int nj = 0; nj < 4; nj++)
          acc_o[mi][nj] = MFMA16(pf[mi], vf[nj], acc_o[mi][nj]);
    }

    if (it + 1 < 32) STAGE(cur ^ 1, (it + 1) * 64);
  }

#pragma unroll
  for (int mi = 0; mi < 2; mi++) {
    const float rl = 1.0f / lq[mi];
#pragma unroll
    for (int r = 0; r < 4; r++) {
      const float rn = __shfl(rl, lg * 4 + r, 16);
      const int q = q0 + mi * 16 + lg * 4 + r;
#pragma unroll
      for (int nj = 0; nj < 4; nj++)
        dots[(size_t)(b * Ss + q) * Dm + h * 64 + nj * 16 + l15] =
            f2bf(acc_o[mi][nj][r] * rn);
    }
  }
}

extern "C" void kernel_launch(void* const* d_in, const int* in_sizes, int n_in,
                              void* d_out, int out_size, void* d_ws, size_t ws_size,
                              hipStream_t stream) {
  const float* tokens = (const float*)d_in[0];
  const float* ln_g = (const float*)d_in[1];
  const float* ln_b = (const float*)d_in[2];
  const float* w_qkv = (const float*)d_in[3];
  const float* w_proj = (const float*)d_in[4];
  const float* b_proj = (const float*)d_in[5];
  float* out = (float*)d_out;

  char* ws = (char*)d_ws;
  unsigned short* x_bf = (unsigned short*)(ws);              // 8 MB (reused as dots)
  unsigned short* wqkvT = (unsigned short*)(ws + 8388608);   // 6 MB
  unsigned short* wprojT = (unsigned short*)(ws + 14680064); // 2 MB
  unsigned short* qkvraw = (unsigned short*)(ws + 16777216); // 24 MB
  unsigned short* vt = (unsigned short*)(ws + 41943040);     // 8 MB
  unsigned short* dots = x_bf;

  ln_kernel<<<4096, 256, 0, stream>>>(tokens, ln_g, ln_b, x_bf);
  transpose_kernel<<<dim3(3072 / 32, 1024 / 32), 256, 0, stream>>>(w_qkv, wqkvT, 1024, 3072);
  transpose_kernel<<<dim3(1024 / 32, 1024 / 32), 256, 0, stream>>>(w_proj, wprojT, 1024, 1024);
  gemm_kernel<0><<<768, 256, 0, stream>>>(
      x_bf, wqkvT, 3072, 1024, 24, qkvraw, nullptr, nullptr, nullptr);
  vtrans_kernel<<<1024, 256, 0, stream>>>(qkvraw, vt);
  attn_kernel<<<512, 256, 0, stream>>>(qkvraw, vt, dots);
  gemm_kernel<1><<<256, 256, 0, stream>>>(
      dots, wprojT, 1024, 1024, 8, nullptr, out, b_proj, tokens);
}